// Round 14
// baseline (720.338 us; speedup 1.0000x reference)
//
#include <hip/hip_runtime.h>

#define N_NODES 50000
#define N_EDGES 1600000
#define F_NODE 64
#define F_EDGE 32
#define MSG 32
#define EDGE_IN 160                       // 2*F_NODE + F_EDGE
#define NF_ELEMS (N_NODES * F_NODE)       // 3,200,000
#define WE_ELEMS (EDGE_IN * MSG)          // 5,120
#define EF_ELEMS (N_EDGES * F_EDGE)       // 51,200,000
#define NSUB 4                            // sub-histograms per node
#define NGRP (N_NODES * NSUB)             // 200,000 counter groups

typedef __attribute__((ext_vector_type(8))) short short8_t;   // 8 bf16
typedef __attribute__((ext_vector_type(4))) float f32x4_t;    // MFMA acc

// ---------------------------------------------------------------------------
// bf16 helpers (RNE)
// ---------------------------------------------------------------------------
__device__ __forceinline__ unsigned short f2bf(float f) {
    unsigned u = __float_as_uint(f);
    return (unsigned short)((u + 0x7FFFu + ((u >> 16) & 1u)) >> 16);
}
__device__ __forceinline__ float bf_lo(unsigned w) { return __uint_as_float(w << 16); }
__device__ __forceinline__ float bf_hi(unsigned w) { return __uint_as_float(w & 0xFFFF0000u); }

__device__ __forceinline__ uint4 pack8(const float4 a, const float4 b) {
    uint4 o;
    o.x = (unsigned)f2bf(a.x) | ((unsigned)f2bf(a.y) << 16);
    o.y = (unsigned)f2bf(a.z) | ((unsigned)f2bf(a.w) << 16);
    o.z = (unsigned)f2bf(b.x) | ((unsigned)f2bf(b.y) << 16);
    o.w = (unsigned)f2bf(b.z) | ((unsigned)f2bf(b.w) << 16);
    return o;
}

// ---------------------------------------------------------------------------
// Phase 0: nf -> nfb (bf16), We -> Webb (bf16), zero cnt4 (folded memset)
// ---------------------------------------------------------------------------
__global__ __launch_bounds__(256) void conv_all(
    const float* __restrict__ nf, const float* __restrict__ We,
    unsigned short* __restrict__ nfb, unsigned short* __restrict__ Webb,
    int* __restrict__ cnt4)
{
    const int tid = blockIdx.x * 256 + threadIdx.x;
    if (tid < NGRP) cnt4[tid] = 0;        // grid 1565*256 = 400,640 >= 200,000
    const int i = tid * 8;
    if (i < NF_ELEMS) {
        *reinterpret_cast<uint4*>(nfb + i) =
            pack8(*reinterpret_cast<const float4*>(nf + i),
                  *reinterpret_cast<const float4*>(nf + i + 4));
    } else if (i < NF_ELEMS + WE_ELEMS) {
        const int j = i - NF_ELEMS;
        *reinterpret_cast<uint4*>(Webb + j) =
            pack8(*reinterpret_cast<const float4*>(We + j),
                  *reinterpret_cast<const float4*>(We + j + 4));
    }
}

// ---------------------------------------------------------------------------
// Phase 1a (EFB path): rank atomics into 4-way sub-histograms (h = e&3,
// node-major layout -> per-address conflict depth 32 -> ~8) FUSED with
// ef->efb conversion. Spread layout 1-atomic-per-4-threads (r8-proven).
// ---------------------------------------------------------------------------
__global__ __launch_bounds__(256) void hist_rank_conv(
    const int* __restrict__ eidx, int* __restrict__ cnt4, int* __restrict__ rank,
    const float* __restrict__ ef, unsigned short* __restrict__ efb)
{
    const int t = blockIdx.x * 256 + threadIdx.x;
    if ((t & 3) == 0) {
        const int e = t >> 2;                 // covers [0, N_EDGES) exactly
        rank[e] = atomicAdd(&cnt4[(eidx[e] << 2) | (e & 3)], 1);
    }
    const int i = t * 8;
    if (i < EF_ELEMS) {
        *reinterpret_cast<uint4*>(efb + i) =
            pack8(*reinterpret_cast<const float4*>(ef + i),
                  *reinterpret_cast<const float4*>(ef + i + 4));
    }
}

// ---------------------------------------------------------------------------
// Phase 1b (no-EFB path): rank atomics only, same sub-histogram scheme
// ---------------------------------------------------------------------------
__global__ __launch_bounds__(256) void hist_rank(
    const int* __restrict__ eidx, int* __restrict__ cnt4, int* __restrict__ rank)
{
    const int e = blockIdx.x * 256 + threadIdx.x;   // grid exact
    rank[e] = atomicAdd(&cnt4[(eidx[e] << 2) | (e & 3)], 1);
}

// ---------------------------------------------------------------------------
// Phase 2: single-block exclusive scan cnt4 -> base4 over 200K groups.
// Node-major group order means node n's msgb segment = [base4[4n], base4[4n+4]).
// ---------------------------------------------------------------------------
__global__ __launch_bounds__(1024) void scan_kernel(
    int* __restrict__ cnt_cursor, int* __restrict__ base)
{
    __shared__ int part[1024];
    const int t = threadIdx.x;
    const int CH = (NGRP + 1023) / 1024;   // 196
    const int lo = t * CH;
    const int hi = min(lo + CH, NGRP);
    int s = 0;
    for (int i = lo; i < hi; ++i) s += cnt_cursor[i];
    part[t] = s;
    __syncthreads();
    for (int off = 1; off < 1024; off <<= 1) {
        int u = (t >= off) ? part[t - off] : 0;
        __syncthreads();
        part[t] += u;
        __syncthreads();
    }
    int run = part[t] - s;
    for (int i = lo; i < hi; ++i) {
        int c = cnt_cursor[i];
        base[i] = run;
        cnt_cursor[i] = run;
        run += c;
    }
    if (t == 1023) base[NGRP] = part[1023];   // total = N_EDGES
}

// ---------------------------------------------------------------------------
// Phase 3: edge MLP via MFMA, original edge order.
// slot = base4[(n0<<2)|(e&3)] + rank[e]  (r8-proven structure otherwise).
//  A-frag (per lane): row = l&15 (edge in tile), k = (l>>4)*8 + j
//  B-frag (per lane): col = l&15, same k                (Webb wave-preloaded)
//  C/D   (verified m89): col = l&15, row = (l>>4)*4 + reg
// ---------------------------------------------------------------------------
template <bool EFB>
__global__ __launch_bounds__(256) void edge_mlp_mfma(
    const unsigned short* __restrict__ nfb,
    const int* __restrict__ eidx,
    const int* __restrict__ rank,
    const int* __restrict__ base4,
    const float* __restrict__ ef,
    const unsigned short* __restrict__ efb,
    const unsigned short* __restrict__ Webb,   // [160][32] bf16 row-major
    const float* __restrict__ be,              // [32] fp32
    unsigned short* __restrict__ msgb)         // [N_EDGES][32] bf16, CSR order
{
    __shared__ unsigned short cbuf[4][16 * MSG];   // per-wave private 1KB
    const int l   = threadIdx.x & 63;
    const int w   = threadIdx.x >> 6;
    const int col = l & 15;
    const int g   = l >> 4;

    // ---- B fragments: 5 K-steps x 2 N-tiles, loaded once per wave ----
    short8_t bfrag[5][2];
    #pragma unroll
    for (int s = 0; s < 5; ++s) {
        #pragma unroll
        for (int t = 0; t < 2; ++t) {
            short8_t v;
            #pragma unroll
            for (int j = 0; j < 8; ++j)
                v[j] = (short)Webb[s * 1024 + g * 256 + j * 32 + t * 16 + col];
            bfrag[s][t] = v;
        }
    }
    const float be0 = be[col];
    const float be1 = be[col + 16];

    const int wid = blockIdx.x * 4 + w;
    const int nw  = gridDim.x * 4;
    const int NT  = N_EDGES / 16;   // 100000 tiles, exact

    for (int tile = wid; tile < NT; tile += nw) {
        const int e  = tile * 16 + col;          // lane serves edge row (l&15)
        const int n0 = eidx[e];                  // coalesced
        const int n1 = eidx[N_EDGES + e];        // coalesced
        const int slot = base4[(n0 << 2) | (e & 3)] + rank[e];

        const unsigned short* r0 = nfb + (size_t)n0 * F_NODE;
        const unsigned short* r1 = nfb + (size_t)n1 * F_NODE;
        const short8_t a0 = *reinterpret_cast<const short8_t*>(r0 + g * 8);        // k 0..31
        const short8_t a1 = *reinterpret_cast<const short8_t*>(r0 + 32 + g * 8);   // k 32..63
        const short8_t a2 = *reinterpret_cast<const short8_t*>(r1 + g * 8);        // k 64..95
        const short8_t a3 = *reinterpret_cast<const short8_t*>(r1 + 32 + g * 8);   // k 96..127

        short8_t a4;
        if (EFB) {
            a4 = *reinterpret_cast<const short8_t*>(efb + (size_t)e * F_EDGE + g * 8);
        } else {
            const float* re = ef + (size_t)e * F_EDGE + g * 8;   // sequential rows
            const float4 e0 = *reinterpret_cast<const float4*>(re);
            const float4 e1 = *reinterpret_cast<const float4*>(re + 4);
            a4[0] = (short)f2bf(e0.x); a4[1] = (short)f2bf(e0.y);
            a4[2] = (short)f2bf(e0.z); a4[3] = (short)f2bf(e0.w);
            a4[4] = (short)f2bf(e1.x); a4[5] = (short)f2bf(e1.y);
            a4[6] = (short)f2bf(e1.z); a4[7] = (short)f2bf(e1.w);
        }

        f32x4_t acc0 = {be0, be0, be0, be0};
        f32x4_t acc1 = {be1, be1, be1, be1};
        acc0 = __builtin_amdgcn_mfma_f32_16x16x32_bf16(a0, bfrag[0][0], acc0, 0, 0, 0);
        acc1 = __builtin_amdgcn_mfma_f32_16x16x32_bf16(a0, bfrag[0][1], acc1, 0, 0, 0);
        acc0 = __builtin_amdgcn_mfma_f32_16x16x32_bf16(a1, bfrag[1][0], acc0, 0, 0, 0);
        acc1 = __builtin_amdgcn_mfma_f32_16x16x32_bf16(a1, bfrag[1][1], acc1, 0, 0, 0);
        acc0 = __builtin_amdgcn_mfma_f32_16x16x32_bf16(a2, bfrag[2][0], acc0, 0, 0, 0);
        acc1 = __builtin_amdgcn_mfma_f32_16x16x32_bf16(a2, bfrag[2][1], acc1, 0, 0, 0);
        acc0 = __builtin_amdgcn_mfma_f32_16x16x32_bf16(a3, bfrag[3][0], acc0, 0, 0, 0);
        acc1 = __builtin_amdgcn_mfma_f32_16x16x32_bf16(a3, bfrag[3][1], acc1, 0, 0, 0);
        acc0 = __builtin_amdgcn_mfma_f32_16x16x32_bf16(a4, bfrag[4][0], acc0, 0, 0, 0);
        acc1 = __builtin_amdgcn_mfma_f32_16x16x32_bf16(a4, bfrag[4][1], acc1, 0, 0, 0);

        // ---- ReLU + bf16 pack, stage via per-wave LDS, scatter 64B rows ----
        unsigned short* cb = cbuf[w];
        #pragma unroll
        for (int r = 0; r < 4; ++r) {
            const int row = g * 4 + r;               // edge row within tile
            cb[row * MSG + col]      = f2bf(fmaxf(acc0[r], 0.0f));
            cb[row * MSG + 16 + col] = f2bf(fmaxf(acc1[r], 0.0f));
        }
        asm volatile("s_waitcnt lgkmcnt(0)" ::: "memory");   // same-wave RAW
        const int dslot = __shfl(slot, l >> 2, 64);          // row (l>>2)'s slot
        const uint4 vv = *reinterpret_cast<const uint4*>(cb + (l >> 2) * MSG + (l & 3) * 8);
        *reinterpret_cast<uint4*>(
            msgb + (size_t)dslot * MSG + (l & 3) * 8) = vv;
        asm volatile("" ::: "memory");               // keep next iter's writes after read
    }
}

// ---------------------------------------------------------------------------
// Phase 4: wave-per-node segmented sum + node MLP  (proven r4-r13).
// Node n's segment = [base4[4n], base4[4n+4])  (node-major groups).
// ---------------------------------------------------------------------------
__global__ __launch_bounds__(256) void node_agg_mlp(
    const float* __restrict__ nf,
    const unsigned short* __restrict__ msgb,
    const int* __restrict__ base4,
    const float* __restrict__ Wn,   // [96][64] row-major
    const float* __restrict__ bn,   // [64]
    float* __restrict__ out)        // [N_NODES][64]
{
    __shared__ float xbuf[4][96];
    const int lane = threadIdx.x & 63;
    const int w    = threadIdx.x >> 6;
    int n = blockIdx.x * 4 + w;                    // grid exact: 50000/4
    n = __builtin_amdgcn_readfirstlane(n);

    const int start = base4[n * 4];
    const int end   = base4[n * 4 + 4];
    const int r = lane >> 2;        // 0..15
    const int q = lane & 3;         // 0..3

    float part[8];
    #pragma unroll
    for (int i = 0; i < 8; ++i) part[i] = 0.0f;

    for (int i = start + r; i < end; i += 16) {
        const uint4 v = reinterpret_cast<const uint4*>(msgb + (size_t)i * MSG)[q];
        part[0] += bf_lo(v.x); part[1] += bf_hi(v.x);
        part[2] += bf_lo(v.y); part[3] += bf_hi(v.y);
        part[4] += bf_lo(v.z); part[5] += bf_hi(v.z);
        part[6] += bf_lo(v.w); part[7] += bf_hi(v.w);
    }
    #pragma unroll
    for (int d = 4; d < 64; d <<= 1) {
        #pragma unroll
        for (int i = 0; i < 8; ++i) part[i] += __shfl_xor(part[i], d, 64);
    }

    float* xb = xbuf[w];
    xb[lane] = nf[(size_t)n * F_NODE + lane];
    if (r == 0) {
        #pragma unroll
        for (int i = 0; i < 8; ++i) xb[F_NODE + q * 8 + i] = part[i];
    }
    __syncthreads();

    float acc = bn[lane];
    #pragma unroll 8
    for (int k = 0; k < F_NODE + MSG; ++k)
        acc = fmaf(Wn[k * F_NODE + lane], xb[k], acc);

    out[(size_t)n * F_NODE + lane] = fmaxf(acc, 0.0f);
}

// ===========================================================================
// Fallback (round-1, proven): direct f32 atomic scatter + thread-per-node MLP
// ===========================================================================
__global__ __launch_bounds__(256) void edge_mlp_atomic(
    const float* __restrict__ nf, const int* __restrict__ eidx,
    const float* __restrict__ ef, const float* __restrict__ We,
    const float* __restrict__ be, float* __restrict__ msum)
{
    const int e = blockIdx.x * 256 + threadIdx.x;
    const int n0 = eidx[e];
    const int n1 = eidx[N_EDGES + e];
    const float4* x0 = reinterpret_cast<const float4*>(nf + (size_t)n0 * F_NODE);
    const float4* x1 = reinterpret_cast<const float4*>(nf + (size_t)n1 * F_NODE);
    const float4* xe = reinterpret_cast<const float4*>(ef + (size_t)e * F_EDGE);
    float acc[MSG];
    #pragma unroll
    for (int j = 0; j < MSG; ++j) acc[j] = be[j];
    #pragma unroll 2
    for (int c = 0; c < 16; ++c) {
        float4 v = x0[c];
        #pragma unroll
        for (int dk = 0; dk < 4; ++dk) {
            const float xv = (&v.x)[dk]; const int k = c * 4 + dk;
            #pragma unroll
            for (int j = 0; j < MSG; ++j) acc[j] = fmaf(We[k * MSG + j], xv, acc[j]);
        }
    }
    #pragma unroll 2
    for (int c = 0; c < 16; ++c) {
        float4 v = x1[c];
        #pragma unroll
        for (int dk = 0; dk < 4; ++dk) {
            const float xv = (&v.x)[dk]; const int k = 64 + c * 4 + dk;
            #pragma unroll
            for (int j = 0; j < MSG; ++j) acc[j] = fmaf(We[k * MSG + j], xv, acc[j]);
        }
    }
    #pragma unroll 2
    for (int c = 0; c < 8; ++c) {
        float4 v = xe[c];
        #pragma unroll
        for (int dk = 0; dk < 4; ++dk) {
            const float xv = (&v.x)[dk]; const int k = 128 + c * 4 + dk;
            #pragma unroll
            for (int j = 0; j < MSG; ++j) acc[j] = fmaf(We[k * MSG + j], xv, acc[j]);
        }
    }
    float* dst = msum + (size_t)n0 * MSG;
    #pragma unroll
    for (int j = 0; j < MSG; ++j) unsafeAtomicAdd(dst + j, fmaxf(acc[j], 0.0f));
}

__global__ __launch_bounds__(256) void node_mlp_thread(
    const float* __restrict__ nf, const float* __restrict__ msum,
    const float* __restrict__ Wn, const float* __restrict__ bn,
    float* __restrict__ out)
{
    const int n = blockIdx.x * 256 + threadIdx.x;
    if (n >= N_NODES) return;
    const float4* x0 = reinterpret_cast<const float4*>(nf + (size_t)n * F_NODE);
    const float4* x1 = reinterpret_cast<const float4*>(msum + (size_t)n * MSG);
    float acc[F_NODE];
    #pragma unroll
    for (int j = 0; j < F_NODE; ++j) acc[j] = bn[j];
    #pragma unroll 2
    for (int c = 0; c < 16; ++c) {
        float4 v = x0[c];
        #pragma unroll
        for (int dk = 0; dk < 4; ++dk) {
            const float xv = (&v.x)[dk]; const int k = c * 4 + dk;
            #pragma unroll
            for (int j = 0; j < F_NODE; ++j) acc[j] = fmaf(Wn[k * F_NODE + j], xv, acc[j]);
        }
    }
    #pragma unroll 2
    for (int c = 0; c < 8; ++c) {
        float4 v = x1[c];
        #pragma unroll
        for (int dk = 0; dk < 4; ++dk) {
            const float xv = (&v.x)[dk]; const int k = 64 + c * 4 + dk;
            #pragma unroll
            for (int j = 0; j < F_NODE; ++j) acc[j] = fmaf(Wn[k * F_NODE + j], xv, acc[j]);
        }
    }
    float4* o = reinterpret_cast<float4*>(out + (size_t)n * F_NODE);
    #pragma unroll
    for (int cc = 0; cc < 16; ++cc) {
        float4 v;
        v.x = fmaxf(acc[cc * 4 + 0], 0.0f);
        v.y = fmaxf(acc[cc * 4 + 1], 0.0f);
        v.z = fmaxf(acc[cc * 4 + 2], 0.0f);
        v.w = fmaxf(acc[cc * 4 + 3], 0.0f);
        o[cc] = v;
    }
}

// ===========================================================================
extern "C" void kernel_launch(void* const* d_in, const int* in_sizes, int n_in,
                              void* d_out, int out_size, void* d_ws, size_t ws_size,
                              hipStream_t stream) {
    const float* nf = (const float*)d_in[0];
    const int*   ei = (const int*)d_in[1];
    const float* ef = (const float*)d_in[2];
    const float* We = (const float*)d_in[3];
    const float* be = (const float*)d_in[4];
    const float* Wn = (const float*)d_in[5];
    const float* bn = (const float*)d_in[6];
    float* out = (float*)d_out;

    // ws: [msgb bf16 E*32][base4 NGRP+1][cnt4 NGRP][pad][nfb][Webb][pad][rank i32 E][pad][efb bf16 E*32]
    size_t off_base = (size_t)N_EDGES * MSG * sizeof(unsigned short);     // 102.4 MB
    size_t off_cnt  = off_base + (size_t)(NGRP + 1) * sizeof(int);
    size_t off_nfb  = (off_cnt + (size_t)NGRP * sizeof(int) + 15) & ~(size_t)15;
    size_t off_webb = off_nfb + (size_t)NF_ELEMS * sizeof(unsigned short);
    size_t off_rank = (off_webb + (size_t)WE_ELEMS * sizeof(unsigned short) + 15) & ~(size_t)15;
    size_t off_efb  = (off_rank + (size_t)N_EDGES * sizeof(int) + 15) & ~(size_t)15;
    const size_t need_r6  = off_efb;                                            // ~116.9 MB
    const size_t need_efb = off_efb + (size_t)EF_ELEMS * sizeof(unsigned short); // ~219.3 MB

    if (ws_size >= need_r6) {
        char* ws = (char*)d_ws;
        unsigned short* msgb  = (unsigned short*)ws;
        int*            basep = (int*)(ws + off_base);
        int*            cnt4  = (int*)(ws + off_cnt);
        unsigned short* nfb   = (unsigned short*)(ws + off_nfb);
        unsigned short* Webb  = (unsigned short*)(ws + off_webb);
        int*            rank  = (int*)(ws + off_rank);
        unsigned short* efb   = (unsigned short*)(ws + off_efb);

        const bool use_efb = (ws_size >= need_efb);

        conv_all<<<(NF_ELEMS + WE_ELEMS) / 8 / 256, 256, 0, stream>>>(nf, We, nfb, Webb, cnt4);
        if (use_efb) {
            hist_rank_conv<<<EF_ELEMS / 8 / 256, 256, 0, stream>>>(ei, cnt4, rank, ef, efb);
            scan_kernel<<<1, 1024, 0, stream>>>(cnt4, basep);
            edge_mlp_mfma<true><<<2048, 256, 0, stream>>>(
                nfb, ei, rank, basep, ef, efb, Webb, be, msgb);
        } else {
            hist_rank<<<N_EDGES / 256, 256, 0, stream>>>(ei, cnt4, rank);
            scan_kernel<<<1, 1024, 0, stream>>>(cnt4, basep);
            edge_mlp_mfma<false><<<2048, 256, 0, stream>>>(
                nfb, ei, rank, basep, ef, efb, Webb, be, msgb);
        }
        node_agg_mlp<<<N_NODES / 4, 256, 0, stream>>>(nf, msgb, basep, Wn, bn, out);
    } else {
        float* msum = (float*)d_ws;
        (void)hipMemsetAsync(msum, 0, (size_t)N_NODES * MSG * sizeof(float), stream);
        edge_mlp_atomic<<<N_EDGES / 256, 256, 0, stream>>>(nf, ei, ef, We, be, msum);
        node_mlp_thread<<<(N_NODES + 255) / 256, 256, 0, stream>>>(nf, msum, Wn, bn, out);
    }
}

// Round 15
// 273.094 us; speedup vs baseline: 2.6377x; 2.6377x over previous
//
#include <hip/hip_runtime.h>

#define N_NODES 50000
#define N_EDGES 1600000
#define F_NODE 64
#define F_EDGE 32
#define MSG 32
#define EDGE_IN 160                       // 2*F_NODE + F_EDGE
#define NF_ELEMS (N_NODES * F_NODE)       // 3,200,000
#define WE_ELEMS (EDGE_IN * MSG)          // 5,120
#define EF_ELEMS (N_EDGES * F_EDGE)       // 51,200,000
#define NSUB 4                            // sub-histograms per node
#define NGRP (N_NODES * NSUB)             // 200,000 counter groups
#define SCAN_ELEMS 1024                   // counters per scan block
#define SCAN_BLOCKS ((NGRP + SCAN_ELEMS - 1) / SCAN_ELEMS)   // 196

typedef __attribute__((ext_vector_type(8))) short short8_t;   // 8 bf16
typedef __attribute__((ext_vector_type(4))) float f32x4_t;    // MFMA acc

// ---------------------------------------------------------------------------
// bf16 helpers (RNE)
// ---------------------------------------------------------------------------
__device__ __forceinline__ unsigned short f2bf(float f) {
    unsigned u = __float_as_uint(f);
    return (unsigned short)((u + 0x7FFFu + ((u >> 16) & 1u)) >> 16);
}
__device__ __forceinline__ float bf_lo(unsigned w) { return __uint_as_float(w << 16); }
__device__ __forceinline__ float bf_hi(unsigned w) { return __uint_as_float(w & 0xFFFF0000u); }

__device__ __forceinline__ uint4 pack8(const float4 a, const float4 b) {
    uint4 o;
    o.x = (unsigned)f2bf(a.x) | ((unsigned)f2bf(a.y) << 16);
    o.y = (unsigned)f2bf(a.z) | ((unsigned)f2bf(a.w) << 16);
    o.z = (unsigned)f2bf(b.x) | ((unsigned)f2bf(b.y) << 16);
    o.w = (unsigned)f2bf(b.z) | ((unsigned)f2bf(b.w) << 16);
    return o;
}

// ---------------------------------------------------------------------------
// Phase 0: nf -> nfb (bf16), We -> Webb (bf16), zero cnt4 (folded memset)
// ---------------------------------------------------------------------------
__global__ __launch_bounds__(256) void conv_all(
    const float* __restrict__ nf, const float* __restrict__ We,
    unsigned short* __restrict__ nfb, unsigned short* __restrict__ Webb,
    int* __restrict__ cnt4)
{
    const int tid = blockIdx.x * 256 + threadIdx.x;
    if (tid < NGRP) cnt4[tid] = 0;        // grid 1565*256 = 400,640 >= 200,000
    const int i = tid * 8;
    if (i < NF_ELEMS) {
        *reinterpret_cast<uint4*>(nfb + i) =
            pack8(*reinterpret_cast<const float4*>(nf + i),
                  *reinterpret_cast<const float4*>(nf + i + 4));
    } else if (i < NF_ELEMS + WE_ELEMS) {
        const int j = i - NF_ELEMS;
        *reinterpret_cast<uint4*>(Webb + j) =
            pack8(*reinterpret_cast<const float4*>(We + j),
                  *reinterpret_cast<const float4*>(We + j + 4));
    }
}

// ---------------------------------------------------------------------------
// Phase 1a (EFB path): rank atomics into 4-way sub-histograms (h = e&3,
// node-major) FUSED with ef->efb conversion (r14-proven, passed).
// ---------------------------------------------------------------------------
__global__ __launch_bounds__(256) void hist_rank_conv(
    const int* __restrict__ eidx, int* __restrict__ cnt4, int* __restrict__ rank,
    const float* __restrict__ ef, unsigned short* __restrict__ efb)
{
    const int t = blockIdx.x * 256 + threadIdx.x;
    if ((t & 3) == 0) {
        const int e = t >> 2;                 // covers [0, N_EDGES) exactly
        rank[e] = atomicAdd(&cnt4[(eidx[e] << 2) | (e & 3)], 1);
    }
    const int i = t * 8;
    if (i < EF_ELEMS) {
        *reinterpret_cast<uint4*>(efb + i) =
            pack8(*reinterpret_cast<const float4*>(ef + i),
                  *reinterpret_cast<const float4*>(ef + i + 4));
    }
}

// ---------------------------------------------------------------------------
// Phase 1b (no-EFB path): rank atomics only, same sub-histogram scheme
// ---------------------------------------------------------------------------
__global__ __launch_bounds__(256) void hist_rank(
    const int* __restrict__ eidx, int* __restrict__ cnt4, int* __restrict__ rank)
{
    const int e = blockIdx.x * 256 + threadIdx.x;   // grid exact
    rank[e] = atomicAdd(&cnt4[(eidx[e] << 2) | (e & 3)], 1);
}

// ---------------------------------------------------------------------------
// Phase 2: hierarchical exclusive scan of cnt4[NGRP] -> base4[NGRP+1].
// Replaces the single-block scan (470us at 200K groups: 1 CU, uncoalesced).
// 2a: per-block reduce (coalesced int4). 2b: scan 196 partials. 2c: per-block
// exclusive scan + offset, write base4 (int4).
// ---------------------------------------------------------------------------
__global__ __launch_bounds__(256) void scan_part(
    const int* __restrict__ cnt4, int* __restrict__ part)
{
    __shared__ int sm[256];
    const int t = threadIdx.x;
    const int idx = blockIdx.x * SCAN_ELEMS + t * 4;
    int s = 0;
    if (idx < NGRP) {                       // NGRP % 4 == 0
        const int4 v = *reinterpret_cast<const int4*>(cnt4 + idx);
        s = v.x + v.y + v.z + v.w;
    }
    sm[t] = s;
    __syncthreads();
    for (int off = 128; off > 0; off >>= 1) {
        if (t < off) sm[t] += sm[t + off];
        __syncthreads();
    }
    if (t == 0) part[blockIdx.x] = sm[0];
}

__global__ __launch_bounds__(256) void scan_mid(int* __restrict__ part)
{
    __shared__ int sm[256];
    const int t = threadIdx.x;
    const int v = (t < SCAN_BLOCKS) ? part[t] : 0;
    sm[t] = v;
    __syncthreads();
    for (int off = 1; off < 256; off <<= 1) {
        const int u = (t >= off) ? sm[t - off] : 0;
        __syncthreads();
        sm[t] += u;
        __syncthreads();
    }
    if (t < SCAN_BLOCKS) part[t] = sm[t] - v;   // exclusive
}

__global__ __launch_bounds__(256) void scan_final(
    const int* __restrict__ cnt4, const int* __restrict__ part,
    int* __restrict__ base4)
{
    __shared__ int sm[256];
    const int t = threadIdx.x;
    const int b = blockIdx.x;
    const int idx = b * SCAN_ELEMS + t * 4;
    int4 v = make_int4(0, 0, 0, 0);
    const bool ok = (idx < NGRP);
    if (ok) v = *reinterpret_cast<const int4*>(cnt4 + idx);
    const int s = v.x + v.y + v.z + v.w;
    sm[t] = s;
    __syncthreads();
    for (int off = 1; off < 256; off <<= 1) {
        const int u = (t >= off) ? sm[t - off] : 0;
        __syncthreads();
        sm[t] += u;
        __syncthreads();
    }
    const int pre = sm[t] - s + part[b];    // exclusive prefix of this int4
    if (ok) {
        int4 o;
        o.x = pre;
        o.y = pre + v.x;
        o.z = pre + v.x + v.y;
        o.w = pre + v.x + v.y + v.z;
        *reinterpret_cast<int4*>(base4 + idx) = o;
    }
    if (b == SCAN_BLOCKS - 1 && t == 255) base4[NGRP] = part[b] + sm[255];
}

// ---------------------------------------------------------------------------
// Phase 3: edge MLP via MFMA (r14-proven, passed).
// slot = base4[(n0<<2)|(e&3)] + rank[e].
//  A-frag (per lane): row = l&15 (edge in tile), k = (l>>4)*8 + j
//  B-frag (per lane): col = l&15, same k                (Webb wave-preloaded)
//  C/D   (verified m89): col = l&15, row = (l>>4)*4 + reg
// ---------------------------------------------------------------------------
template <bool EFB>
__global__ __launch_bounds__(256) void edge_mlp_mfma(
    const unsigned short* __restrict__ nfb,
    const int* __restrict__ eidx,
    const int* __restrict__ rank,
    const int* __restrict__ base4,
    const float* __restrict__ ef,
    const unsigned short* __restrict__ efb,
    const unsigned short* __restrict__ Webb,   // [160][32] bf16 row-major
    const float* __restrict__ be,              // [32] fp32
    unsigned short* __restrict__ msgb)         // [N_EDGES][32] bf16, CSR order
{
    __shared__ unsigned short cbuf[4][16 * MSG];   // per-wave private 1KB
    const int l   = threadIdx.x & 63;
    const int w   = threadIdx.x >> 6;
    const int col = l & 15;
    const int g   = l >> 4;

    // ---- B fragments: 5 K-steps x 2 N-tiles, loaded once per wave ----
    short8_t bfrag[5][2];
    #pragma unroll
    for (int s = 0; s < 5; ++s) {
        #pragma unroll
        for (int t = 0; t < 2; ++t) {
            short8_t v;
            #pragma unroll
            for (int j = 0; j < 8; ++j)
                v[j] = (short)Webb[s * 1024 + g * 256 + j * 32 + t * 16 + col];
            bfrag[s][t] = v;
        }
    }
    const float be0 = be[col];
    const float be1 = be[col + 16];

    const int wid = blockIdx.x * 4 + w;
    const int nw  = gridDim.x * 4;
    const int NT  = N_EDGES / 16;   // 100000 tiles, exact

    for (int tile = wid; tile < NT; tile += nw) {
        const int e  = tile * 16 + col;          // lane serves edge row (l&15)
        const int n0 = eidx[e];                  // coalesced
        const int n1 = eidx[N_EDGES + e];        // coalesced
        const int slot = base4[(n0 << 2) | (e & 3)] + rank[e];

        const unsigned short* r0 = nfb + (size_t)n0 * F_NODE;
        const unsigned short* r1 = nfb + (size_t)n1 * F_NODE;
        const short8_t a0 = *reinterpret_cast<const short8_t*>(r0 + g * 8);        // k 0..31
        const short8_t a1 = *reinterpret_cast<const short8_t*>(r0 + 32 + g * 8);   // k 32..63
        const short8_t a2 = *reinterpret_cast<const short8_t*>(r1 + g * 8);        // k 64..95
        const short8_t a3 = *reinterpret_cast<const short8_t*>(r1 + 32 + g * 8);   // k 96..127

        short8_t a4;
        if (EFB) {
            a4 = *reinterpret_cast<const short8_t*>(efb + (size_t)e * F_EDGE + g * 8);
        } else {
            const float* re = ef + (size_t)e * F_EDGE + g * 8;   // sequential rows
            const float4 e0 = *reinterpret_cast<const float4*>(re);
            const float4 e1 = *reinterpret_cast<const float4*>(re + 4);
            a4[0] = (short)f2bf(e0.x); a4[1] = (short)f2bf(e0.y);
            a4[2] = (short)f2bf(e0.z); a4[3] = (short)f2bf(e0.w);
            a4[4] = (short)f2bf(e1.x); a4[5] = (short)f2bf(e1.y);
            a4[6] = (short)f2bf(e1.z); a4[7] = (short)f2bf(e1.w);
        }

        f32x4_t acc0 = {be0, be0, be0, be0};
        f32x4_t acc1 = {be1, be1, be1, be1};
        acc0 = __builtin_amdgcn_mfma_f32_16x16x32_bf16(a0, bfrag[0][0], acc0, 0, 0, 0);
        acc1 = __builtin_amdgcn_mfma_f32_16x16x32_bf16(a0, bfrag[0][1], acc1, 0, 0, 0);
        acc0 = __builtin_amdgcn_mfma_f32_16x16x32_bf16(a1, bfrag[1][0], acc0, 0, 0, 0);
        acc1 = __builtin_amdgcn_mfma_f32_16x16x32_bf16(a1, bfrag[1][1], acc1, 0, 0, 0);
        acc0 = __builtin_amdgcn_mfma_f32_16x16x32_bf16(a2, bfrag[2][0], acc0, 0, 0, 0);
        acc1 = __builtin_amdgcn_mfma_f32_16x16x32_bf16(a2, bfrag[2][1], acc1, 0, 0, 0);
        acc0 = __builtin_amdgcn_mfma_f32_16x16x32_bf16(a3, bfrag[3][0], acc0, 0, 0, 0);
        acc1 = __builtin_amdgcn_mfma_f32_16x16x32_bf16(a3, bfrag[3][1], acc1, 0, 0, 0);
        acc0 = __builtin_amdgcn_mfma_f32_16x16x32_bf16(a4, bfrag[4][0], acc0, 0, 0, 0);
        acc1 = __builtin_amdgcn_mfma_f32_16x16x32_bf16(a4, bfrag[4][1], acc1, 0, 0, 0);

        // ---- ReLU + bf16 pack, stage via per-wave LDS, scatter 64B rows ----
        unsigned short* cb = cbuf[w];
        #pragma unroll
        for (int r = 0; r < 4; ++r) {
            const int row = g * 4 + r;               // edge row within tile
            cb[row * MSG + col]      = f2bf(fmaxf(acc0[r], 0.0f));
            cb[row * MSG + 16 + col] = f2bf(fmaxf(acc1[r], 0.0f));
        }
        asm volatile("s_waitcnt lgkmcnt(0)" ::: "memory");   // same-wave RAW
        const int dslot = __shfl(slot, l >> 2, 64);          // row (l>>2)'s slot
        const uint4 vv = *reinterpret_cast<const uint4*>(cb + (l >> 2) * MSG + (l & 3) * 8);
        *reinterpret_cast<uint4*>(
            msgb + (size_t)dslot * MSG + (l & 3) * 8) = vv;
        asm volatile("" ::: "memory");               // keep next iter's writes after read
    }
}

// ---------------------------------------------------------------------------
// Phase 4: wave-per-node segmented sum + node MLP  (r14-proven, passed).
// Node n's segment = [base4[4n], base4[4n+4])  (node-major groups).
// ---------------------------------------------------------------------------
__global__ __launch_bounds__(256) void node_agg_mlp(
    const float* __restrict__ nf,
    const unsigned short* __restrict__ msgb,
    const int* __restrict__ base4,
    const float* __restrict__ Wn,   // [96][64] row-major
    const float* __restrict__ bn,   // [64]
    float* __restrict__ out)        // [N_NODES][64]
{
    __shared__ float xbuf[4][96];
    const int lane = threadIdx.x & 63;
    const int w    = threadIdx.x >> 6;
    int n = blockIdx.x * 4 + w;                    // grid exact: 50000/4
    n = __builtin_amdgcn_readfirstlane(n);

    const int start = base4[n * 4];
    const int end   = base4[n * 4 + 4];
    const int r = lane >> 2;        // 0..15
    const int q = lane & 3;         // 0..3

    float part[8];
    #pragma unroll
    for (int i = 0; i < 8; ++i) part[i] = 0.0f;

    for (int i = start + r; i < end; i += 16) {
        const uint4 v = reinterpret_cast<const uint4*>(msgb + (size_t)i * MSG)[q];
        part[0] += bf_lo(v.x); part[1] += bf_hi(v.x);
        part[2] += bf_lo(v.y); part[3] += bf_hi(v.y);
        part[4] += bf_lo(v.z); part[5] += bf_hi(v.z);
        part[6] += bf_lo(v.w); part[7] += bf_hi(v.w);
    }
    #pragma unroll
    for (int d = 4; d < 64; d <<= 1) {
        #pragma unroll
        for (int i = 0; i < 8; ++i) part[i] += __shfl_xor(part[i], d, 64);
    }

    float* xb = xbuf[w];
    xb[lane] = nf[(size_t)n * F_NODE + lane];
    if (r == 0) {
        #pragma unroll
        for (int i = 0; i < 8; ++i) xb[F_NODE + q * 8 + i] = part[i];
    }
    __syncthreads();

    float acc = bn[lane];
    #pragma unroll 8
    for (int k = 0; k < F_NODE + MSG; ++k)
        acc = fmaf(Wn[k * F_NODE + lane], xb[k], acc);

    out[(size_t)n * F_NODE + lane] = fmaxf(acc, 0.0f);
}

// ===========================================================================
// Fallback (round-1, proven): direct f32 atomic scatter + thread-per-node MLP
// ===========================================================================
__global__ __launch_bounds__(256) void edge_mlp_atomic(
    const float* __restrict__ nf, const int* __restrict__ eidx,
    const float* __restrict__ ef, const float* __restrict__ We,
    const float* __restrict__ be, float* __restrict__ msum)
{
    const int e = blockIdx.x * 256 + threadIdx.x;
    const int n0 = eidx[e];
    const int n1 = eidx[N_EDGES + e];
    const float4* x0 = reinterpret_cast<const float4*>(nf + (size_t)n0 * F_NODE);
    const float4* x1 = reinterpret_cast<const float4*>(nf + (size_t)n1 * F_NODE);
    const float4* xe = reinterpret_cast<const float4*>(ef + (size_t)e * F_EDGE);
    float acc[MSG];
    #pragma unroll
    for (int j = 0; j < MSG; ++j) acc[j] = be[j];
    #pragma unroll 2
    for (int c = 0; c < 16; ++c) {
        float4 v = x0[c];
        #pragma unroll
        for (int dk = 0; dk < 4; ++dk) {
            const float xv = (&v.x)[dk]; const int k = c * 4 + dk;
            #pragma unroll
            for (int j = 0; j < MSG; ++j) acc[j] = fmaf(We[k * MSG + j], xv, acc[j]);
        }
    }
    #pragma unroll 2
    for (int c = 0; c < 16; ++c) {
        float4 v = x1[c];
        #pragma unroll
        for (int dk = 0; dk < 4; ++dk) {
            const float xv = (&v.x)[dk]; const int k = 64 + c * 4 + dk;
            #pragma unroll
            for (int j = 0; j < MSG; ++j) acc[j] = fmaf(We[k * MSG + j], xv, acc[j]);
        }
    }
    #pragma unroll 2
    for (int c = 0; c < 8; ++c) {
        float4 v = xe[c];
        #pragma unroll
        for (int dk = 0; dk < 4; ++dk) {
            const float xv = (&v.x)[dk]; const int k = 128 + c * 4 + dk;
            #pragma unroll
            for (int j = 0; j < MSG; ++j) acc[j] = fmaf(We[k * MSG + j], xv, acc[j]);
        }
    }
    float* dst = msum + (size_t)n0 * MSG;
    #pragma unroll
    for (int j = 0; j < MSG; ++j) unsafeAtomicAdd(dst + j, fmaxf(acc[j], 0.0f));
}

__global__ __launch_bounds__(256) void node_mlp_thread(
    const float* __restrict__ nf, const float* __restrict__ msum,
    const float* __restrict__ Wn, const float* __restrict__ bn,
    float* __restrict__ out)
{
    const int n = blockIdx.x * 256 + threadIdx.x;
    if (n >= N_NODES) return;
    const float4* x0 = reinterpret_cast<const float4*>(nf + (size_t)n * F_NODE);
    const float4* x1 = reinterpret_cast<const float4*>(msum + (size_t)n * MSG);
    float acc[F_NODE];
    #pragma unroll
    for (int j = 0; j < F_NODE; ++j) acc[j] = bn[j];
    #pragma unroll 2
    for (int c = 0; c < 16; ++c) {
        float4 v = x0[c];
        #pragma unroll
        for (int dk = 0; dk < 4; ++dk) {
            const float xv = (&v.x)[dk]; const int k = c * 4 + dk;
            #pragma unroll
            for (int j = 0; j < F_NODE; ++j) acc[j] = fmaf(Wn[k * F_NODE + j], xv, acc[j]);
        }
    }
    #pragma unroll 2
    for (int c = 0; c < 8; ++c) {
        float4 v = x1[c];
        #pragma unroll
        for (int dk = 0; dk < 4; ++dk) {
            const float xv = (&v.x)[dk]; const int k = 64 + c * 4 + dk;
            #pragma unroll
            for (int j = 0; j < F_NODE; ++j) acc[j] = fmaf(Wn[k * F_NODE + j], xv, acc[j]);
        }
    }
    float4* o = reinterpret_cast<float4*>(out + (size_t)n * F_NODE);
    #pragma unroll
    for (int cc = 0; cc < 16; ++cc) {
        float4 v;
        v.x = fmaxf(acc[cc * 4 + 0], 0.0f);
        v.y = fmaxf(acc[cc * 4 + 1], 0.0f);
        v.z = fmaxf(acc[cc * 4 + 2], 0.0f);
        v.w = fmaxf(acc[cc * 4 + 3], 0.0f);
        o[cc] = v;
    }
}

// ===========================================================================
extern "C" void kernel_launch(void* const* d_in, const int* in_sizes, int n_in,
                              void* d_out, int out_size, void* d_ws, size_t ws_size,
                              hipStream_t stream) {
    const float* nf = (const float*)d_in[0];
    const int*   ei = (const int*)d_in[1];
    const float* ef = (const float*)d_in[2];
    const float* We = (const float*)d_in[3];
    const float* be = (const float*)d_in[4];
    const float* Wn = (const float*)d_in[5];
    const float* bn = (const float*)d_in[6];
    float* out = (float*)d_out;

    // ws: [msgb bf16 E*32][base4 NGRP+1][cnt4 NGRP][part SCAN_BLOCKS][pad]
    //     [nfb][Webb][pad][rank i32 E][pad][efb bf16 E*32]
    size_t off_base = (size_t)N_EDGES * MSG * sizeof(unsigned short);     // 102.4 MB
    size_t off_cnt  = off_base + (size_t)(NGRP + 1) * sizeof(int);
    size_t off_part = off_cnt + (size_t)NGRP * sizeof(int);
    size_t off_nfb  = (off_part + (size_t)SCAN_BLOCKS * sizeof(int) + 15) & ~(size_t)15;
    size_t off_webb = off_nfb + (size_t)NF_ELEMS * sizeof(unsigned short);
    size_t off_rank = (off_webb + (size_t)WE_ELEMS * sizeof(unsigned short) + 15) & ~(size_t)15;
    size_t off_efb  = (off_rank + (size_t)N_EDGES * sizeof(int) + 15) & ~(size_t)15;
    const size_t need_r6  = off_efb;                                            // ~116.9 MB
    const size_t need_efb = off_efb + (size_t)EF_ELEMS * sizeof(unsigned short); // ~219.3 MB

    if (ws_size >= need_r6) {
        char* ws = (char*)d_ws;
        unsigned short* msgb  = (unsigned short*)ws;
        int*            basep = (int*)(ws + off_base);
        int*            cnt4  = (int*)(ws + off_cnt);
        int*            part  = (int*)(ws + off_part);
        unsigned short* nfb   = (unsigned short*)(ws + off_nfb);
        unsigned short* Webb  = (unsigned short*)(ws + off_webb);
        int*            rank  = (int*)(ws + off_rank);
        unsigned short* efb   = (unsigned short*)(ws + off_efb);

        const bool use_efb = (ws_size >= need_efb);

        conv_all<<<(NF_ELEMS + WE_ELEMS) / 8 / 256, 256, 0, stream>>>(nf, We, nfb, Webb, cnt4);
        if (use_efb) {
            hist_rank_conv<<<EF_ELEMS / 8 / 256, 256, 0, stream>>>(ei, cnt4, rank, ef, efb);
        } else {
            hist_rank<<<N_EDGES / 256, 256, 0, stream>>>(ei, cnt4, rank);
        }
        scan_part<<<SCAN_BLOCKS, 256, 0, stream>>>(cnt4, part);
        scan_mid<<<1, 256, 0, stream>>>(part);
        scan_final<<<SCAN_BLOCKS, 256, 0, stream>>>(cnt4, part, basep);
        if (use_efb) {
            edge_mlp_mfma<true><<<2048, 256, 0, stream>>>(
                nfb, ei, rank, basep, ef, efb, Webb, be, msgb);
        } else {
            edge_mlp_mfma<false><<<2048, 256, 0, stream>>>(
                nfb, ei, rank, basep, ef, efb, Webb, be, msgb);
        }
        node_agg_mlp<<<N_NODES / 4, 256, 0, stream>>>(nf, msgb, basep, Wn, bn, out);
    } else {
        float* msum = (float*)d_ws;
        (void)hipMemsetAsync(msum, 0, (size_t)N_NODES * MSG * sizeof(float), stream);
        edge_mlp_atomic<<<N_EDGES / 256, 256, 0, stream>>>(nf, ei, ef, We, be, msum);
        node_mlp_thread<<<(N_NODES + 255) / 256, 256, 0, stream>>>(nf, msum, Wn, bn, out);
    }
}